// Round 10
// baseline (668.408 us; speedup 1.0000x reference)
//
#include <hip/hip_runtime.h>
#include <hip/hip_bf16.h>

#define NE   64
#define NH   1024
#define NF   2816
#define TPE  64
#define PITCH 72      // k2 LDS pitch (validated)
#define WP   1032     // k1 LDS pitch (ushorts): bank-minimal for write & b128 read

typedef __attribute__((ext_vector_type(8))) short bf16x8;
typedef __attribute__((ext_vector_type(4))) float f32x4;

__device__ __forceinline__ ushort f2bf(float f) {
    union { float f; unsigned u; } v; v.f = f;
    unsigned r = v.u + 0x7fffu + ((v.u >> 16) & 1u);
    return (ushort)(r >> 16);
}

__device__ __forceinline__ float bf2f(ushort u) {
    union { unsigned u; float f; } v; v.u = ((unsigned)u) << 16;
    return v.f;
}

__device__ __forceinline__ bf16x8 cvt8(f32x4 lo, f32x4 hi) {
    bf16x8 r;
    #pragma unroll
    for (int j = 0; j < 4; ++j) {
        r[j]     = (short)f2bf(lo[j]);
        r[4 + j] = (short)f2bf(hi[j]);
    }
    return r;
}

// ---------------- Kernel 0: x (f32) -> xb (bf16), one pass -----------------
__global__ __launch_bounds__(256)
void xcast(const float* __restrict__ x, ushort* __restrict__ xb) {
    const int i = blockIdx.x * 256 + threadIdx.x;   // 8 elems per thread
    const f32x4 a = *(const f32x4*)(x + (size_t)i * 8);
    const f32x4 b = *(const f32x4*)(x + (size_t)i * 8 + 4);
    *(bf16x8*)(xb + (size_t)i * 8) = cvt8(a, b);
}

// ---- Kernel 1a/1b: x @ w^T with FULLY CONTIGUOUS weight streaming -----------
// Test of the DRAM row-sweep theory: k2 (K = weight ROWS, co-swept) streams at
// ~7 TB/s; all K-=-columns k1 variants pin at ~3.7-4.5. Here each block owns a
// contiguous 704KB slab (176 f-rows x 4KB) and reads it front-to-back in 11
// tiles of 16 FULL rows (1KB-contiguous per wave instruction). grid (16,64) =
// 1024 blocks = exact residency (4 blocks/CU, zero tail); serial 2-barrier
// loop lets the 4 resident blocks anti-phase. A-frags per-lane from
// L2-resident pre-cast xb (validated R7/R9).
// GATE=0: outp = x@w^T (bf16).  GATE=1: outp = silu(h1in) * (x@w^T) (bf16).
template <int GATE>
__global__ __launch_bounds__(256, 4)
void k1_mm(const ushort* __restrict__ xb,
           const float* __restrict__ w,
           const ushort* __restrict__ h1in,
           ushort* __restrict__ outp) {
    __shared__ ushort lW[16 * WP];   // 33 KB -> 4 blocks/CU

    const int jtg  = blockIdx.x;               // f slab (0..15), 176 rows each
    const int e    = blockIdx.y;               // expert
    const int tid  = threadIdx.x;
    const int lane = tid & 63;
    const int wid  = tid >> 6;
    const int m15  = lane & 15;
    const int hi   = lane >> 4;

    // A: this lane's token row (wave wid covers tokens wid*16..wid*16+15)
    const ushort* xA = xb + ((size_t)e * TPE + wid * 16 + m15) * NH;
    // B: contiguous 176-row slab of w[e]
    const float* B = w + ((size_t)e * NF + (size_t)jtg * 176) * NH;

    for (int t = 0; t < 11; ++t) {             // 11 tiles of 16 f-rows
        __syncthreads();                        // prev tile's readers done
        // stage: wave wid reads rows wid*4..wid*4+3 IN FULL (4x 1KB-contig
        // instructions per row), cvt f32->bf16, LDS write (bank-minimal)
        #pragma unroll
        for (int r = 0; r < 4; ++r) {
            const int row = wid * 4 + r;
            const float* src = B + ((size_t)(t * 16 + row)) * NH;
            #pragma unroll
            for (int i = 0; i < 4; ++i) {
                const float4 v = *(const float4*)(src + i * 256 + lane * 4);
                ushort4 u;
                u.x = f2bf(v.x); u.y = f2bf(v.y); u.z = f2bf(v.z); u.w = f2bf(v.w);
                *(ushort4*)(&lW[row * WP + i * 256 + lane * 4]) = u;
            }
        }
        __syncthreads();                        // tile staged

        // compute: 16 tokens x 16 f, full K=1024, one MFMA chain of 32
        f32x4 acc = f32x4{0.f, 0.f, 0.f, 0.f};
        #pragma unroll 8
        for (int kk = 0; kk < 32; ++kk) {
            const int ko = kk * 32 + hi * 8;
            const bf16x8 af = *(const bf16x8*)(xA + ko);          // L2-hot x
            const bf16x8 bw = *(const bf16x8*)(&lW[m15 * WP + ko]);
            acc = __builtin_amdgcn_mfma_f32_16x16x32_bf16(af, bw, acc, 0, 0, 0);
        }

        // epilogue for this tile. C/D: col(m15)=f, row=hi*4+i within wave tokens
        #pragma unroll
        for (int i = 0; i < 4; ++i) {
            const int token = wid * 16 + hi * 4 + i;
            const int fcol  = jtg * 176 + t * 16 + m15;
            const size_t idx = ((size_t)e * TPE + token) * NF + fcol;
            if (GATE) {
                const float h1v = bf2f(h1in[idx]);               // L3-hot
                const float h3v = acc[i];
                const float s   = (h1v / (1.f + __expf(-h1v))) * h3v;
                outp[idx] = f2bf(s);
            } else {
                outp[idx] = f2bf(acc[i]);
            }
        }
    }
}

// ---------------- Kernel 2: out = gated @ w2 (per expert), fp32 out ------------
// (unchanged — single co-swept weight stream at ~7 TB/s; at roofline)
__global__ __launch_bounds__(256, 2)
void k2_down(const ushort* __restrict__ g,
             const float* __restrict__ w2,
             float* __restrict__ out) {
    __shared__ ushort lA[64 * PITCH];
    __shared__ ushort lB[64 * PITCH];

    const int jt   = blockIdx.x;
    const int e    = blockIdx.y;
    const int tid  = threadIdx.x;
    const int lane = tid & 63;
    const int wid  = tid >> 6;

    const ushort* A = g  + (size_t)e * TPE * NF;
    const float*  B = w2 + (size_t)e * NF * NH + (size_t)jt * 64;
    float* O = out + (size_t)e * TPE * NH + (size_t)jt * 64;

    f32x4 acc[4];
    for (int nf = 0; nf < 4; ++nf) acc[nf] = f32x4{0.f, 0.f, 0.f, 0.f};

    for (int kt = 0; kt < NF / 64; ++kt) {   // 44 iters
        __syncthreads();
        #pragma unroll
        for (int r = 0; r < 2; ++r) {
            const int q   = tid + r * 256;
            const int row = q >> 3;
            const int k8  = (q & 7) * 8;
            *(bf16x8*)(&lA[row * PITCH + k8]) =
                *(const bf16x8*)(A + (size_t)row * NF + kt * 64 + k8);
        }
        {
            const int n  = tid & 63;
            const int kq = (tid >> 6) * 4;
            #pragma unroll
            for (int r = 0; r < 4; ++r) {
                const int ks = kq + r * 16;
                const size_t base = (size_t)(kt * 64 + ks) * NH + n;
                const float f0 = B[base];
                const float f1 = B[base + NH];
                const float f2 = B[base + 2 * (size_t)NH];
                const float f3 = B[base + 3 * (size_t)NH];
                ushort4 b;
                b.x = f2bf(f0); b.y = f2bf(f1); b.z = f2bf(f2); b.w = f2bf(f3);
                *(ushort4*)(&lB[n * PITCH + ks]) = b;
            }
        }
        __syncthreads();

        const int mrow = wid * 16 + (lane & 15);
        #pragma unroll
        for (int ks = 0; ks < 2; ++ks) {
            const int koff = ks * 32 + ((lane >> 4) * 8);
            const bf16x8 af = *(const bf16x8*)(&lA[mrow * PITCH + koff]);
            #pragma unroll
            for (int nf = 0; nf < 4; ++nf) {
                const bf16x8 bfr = *(const bf16x8*)(&lB[(nf * 16 + (lane & 15)) * PITCH + koff]);
                acc[nf] = __builtin_amdgcn_mfma_f32_16x16x32_bf16(af, bfr, acc[nf], 0, 0, 0);
            }
        }
    }

    #pragma unroll
    for (int nf = 0; nf < 4; ++nf) {
        #pragma unroll
        for (int i = 0; i < 4; ++i) {
            const int row = wid * 16 + ((lane >> 4) * 4) + i;
            const int col = nf * 16 + (lane & 15);
            O[(size_t)row * NH + col] = acc[nf][i];
        }
    }
}

extern "C" void kernel_launch(void* const* d_in, const int* in_sizes, int n_in,
                              void* d_out, int out_size, void* d_ws, size_t ws_size,
                              hipStream_t stream) {
    const float* x  = (const float*)d_in[0];
    const float* w1 = (const float*)d_in[2];
    const float* w3 = (const float*)d_in[3];
    const float* w2 = (const float*)d_in[4];
    float* out = (float*)d_out;
    ushort* gated = (ushort*)d_ws;                         // 23.1 MB
    ushort* xbf   = (ushort*)((char*)d_ws + (32u << 20));  // 8.4 MB @ +32MB
    ushort* h1    = (ushort*)((char*)d_ws + (48u << 20));  // 23.1 MB @ +48MB

    xcast<<<dim3((TPE * NE * NH) / (256 * 8)), dim3(256), 0, stream>>>(x, xbf);

    dim3 g1(16, NE);         // (16, 64) = 1024 blocks = exact residency
    k1_mm<0><<<g1, dim3(256), 0, stream>>>(xbf, w1, nullptr, h1);   // h1 = x@w1^T
    k1_mm<1><<<g1, dim3(256), 0, stream>>>(xbf, w3, h1, gated);     // gated = silu(h1)*(x@w3^T)

    dim3 g2(NH / 64, NE);    // (16, 64)
    k2_down<<<g2, dim3(256), 0, stream>>>(gated, w2, out);
}

// Round 11
// 490.694 us; speedup vs baseline: 1.3622x; 1.3622x over previous
//
#include <hip/hip_runtime.h>
#include <hip/hip_bf16.h>

#define NE   64
#define NH   1024
#define NF   2816
#define TPE  64
#define PITCH 72      // LDS pitch (validated in k2 at ~7.1 TB/s)

typedef __attribute__((ext_vector_type(8))) short bf16x8;
typedef __attribute__((ext_vector_type(4))) float f32x4;

__device__ __forceinline__ ushort f2bf(float f) {
    union { float f; unsigned u; } v; v.f = f;
    unsigned r = v.u + 0x7fffu + ((v.u >> 16) & 1u);
    return (ushort)(r >> 16);
}

__device__ __forceinline__ float bf2f(ushort u) {
    union { unsigned u; float f; } v; v.u = ((unsigned)u) << 16;
    return v.f;
}

__device__ __forceinline__ bf16x8 cvt8(f32x4 lo, f32x4 hi) {
    bf16x8 r;
    #pragma unroll
    for (int j = 0; j < 4; ++j) {
        r[j]     = (short)f2bf(lo[j]);
        r[4 + j] = (short)f2bf(hi[j]);
    }
    return r;
}

// ---------------- Kernel 0: x (f32) -> xb (bf16), one pass -----------------
__global__ __launch_bounds__(256)
void xcast(const float* __restrict__ x, ushort* __restrict__ xb) {
    const int i = blockIdx.x * 256 + threadIdx.x;   // 8 elems per thread
    const f32x4 a = *(const f32x4*)(x + (size_t)i * 8);
    const f32x4 b = *(const f32x4*)(x + (size_t)i * 8 + 4);
    *(bf16x8*)(xb + (size_t)i * 8) = cvt8(a, b);
}

// ---- Kernel 1a/1b: x @ w^T — k2 CLONE (staging shape + LDS-only compute) ----
// The last two structural diffs vs the 7.1 TB/s k2 are removed:
//  (1) weight staging = k2's exact instruction shape: scalar dwords, one
//      instruction touches 256B inside ONE weight row (n=tid&63 covers 64
//      consecutive cols); rows walked across instructions.
//  (2) compute phase is 100% LDS: x-tile staged bf16 (k2 A-clone, L3-hot xb).
// GATE=0: outp = x@w^T (bf16).  GATE=1: outp = silu(h1in) * (x@w^T) (bf16).
template <int GATE>
__global__ __launch_bounds__(256, 2)
void k1_mm(const ushort* __restrict__ xb,
           const float* __restrict__ w,
           const ushort* __restrict__ h1in,
           ushort* __restrict__ outp) {
    __shared__ ushort lX[64 * PITCH];   // 9.2 KB  [token][k]
    __shared__ ushort lW[64 * PITCH];   // 9.2 KB  [f][k]

    const int jt   = blockIdx.x;               // ff 64-tile (0..43)
    const int e    = blockIdx.y;               // expert
    const int tid  = threadIdx.x;
    const int lane = tid & 63;
    const int wid  = tid >> 6;
    const int m15  = lane & 15;
    const int hi   = lane >> 4;
    const int mrow = wid * 16 + m15;

    const ushort* A = xb + (size_t)e * TPE * NH;                     // [64][1024]
    const float*  B = w  + ((size_t)e * NF + (size_t)jt * 64) * NH;  // [64][1024]

    f32x4 acc[4];
    #pragma unroll
    for (int nf = 0; nf < 4; ++nf) acc[nf] = f32x4{0.f, 0.f, 0.f, 0.f};

    const int n  = tid & 63;           // k-col within chunk (one row per instr)
    const int kq = (tid >> 6) * 4;     // f-row group base for this wave

    for (int kt = 0; kt < NH / 64; ++kt) {     // 16 iters
        __syncthreads();
        // x-stage (k2 A-tile clone): 2 x b128 per thread, bf16 source
        #pragma unroll
        for (int r = 0; r < 2; ++r) {
            const int q   = tid + r * 256;
            const int row = q >> 3;
            const int k8  = (q & 7) * 8;
            *(bf16x8*)(&lX[row * PITCH + k8]) =
                *(const bf16x8*)(A + (size_t)row * NH + kt * 64 + k8);
        }
        // w-stage (k2 B-tile clone): scalar dwords, 1 row x 256B per instr,
        // 4 consecutive rows per round, 4 rounds. Lands untransposed [f][k];
        // u16 LDS writes: 64 lanes x 2B consecutive = wave64 bank minimum.
        #pragma unroll
        for (int r = 0; r < 4; ++r) {
            const int fr = kq + r * 16;
            const size_t base = (size_t)fr * NH + kt * 64 + n;
            const float f0 = B[base];
            const float f1 = B[base + NH];
            const float f2 = B[base + 2 * (size_t)NH];
            const float f3 = B[base + 3 * (size_t)NH];
            lW[(fr + 0) * PITCH + n] = f2bf(f0);
            lW[(fr + 1) * PITCH + n] = f2bf(f1);
            lW[(fr + 2) * PITCH + n] = f2bf(f2);
            lW[(fr + 3) * PITCH + n] = f2bf(f3);
        }
        __syncthreads();

        // compute: 100% LDS (k2-identical geometry)
        #pragma unroll
        for (int ks = 0; ks < 2; ++ks) {
            const int koff = ks * 32 + hi * 8;
            const bf16x8 af = *(const bf16x8*)(&lX[mrow * PITCH + koff]);
            #pragma unroll
            for (int nf = 0; nf < 4; ++nf) {
                const bf16x8 bw = *(const bf16x8*)(&lW[(nf * 16 + m15) * PITCH + koff]);
                acc[nf] = __builtin_amdgcn_mfma_f32_16x16x32_bf16(af, bw, acc[nf], 0, 0, 0);
            }
        }
    }

    // epilogue (validated R9). C/D layout: col=lane&15, row=(lane>>4)*4+i
    #pragma unroll
    for (int nf = 0; nf < 4; ++nf) {
        #pragma unroll
        for (int i = 0; i < 4; ++i) {
            const int row = wid * 16 + hi * 4 + i;
            const int col = jt * 64 + nf * 16 + m15;
            const size_t idx = ((size_t)e * TPE + row) * NF + col;
            if (GATE) {
                const float h1v = bf2f(h1in[idx]);          // L3-hot
                const float h3v = acc[nf][i];
                const float s   = (h1v / (1.f + __expf(-h1v))) * h3v;
                outp[idx] = f2bf(s);
            } else {
                outp[idx] = f2bf(acc[nf][i]);
            }
        }
    }
}

// ---------------- Kernel 2: out = gated @ w2 (per expert), fp32 out ------------
// (unchanged — single co-swept weight stream at ~7.1 TB/s; at roofline)
__global__ __launch_bounds__(256, 2)
void k2_down(const ushort* __restrict__ g,
             const float* __restrict__ w2,
             float* __restrict__ out) {
    __shared__ ushort lA[64 * PITCH];
    __shared__ ushort lB[64 * PITCH];

    const int jt   = blockIdx.x;
    const int e    = blockIdx.y;
    const int tid  = threadIdx.x;
    const int lane = tid & 63;
    const int wid  = tid >> 6;

    const ushort* A = g  + (size_t)e * TPE * NF;
    const float*  B = w2 + (size_t)e * NF * NH + (size_t)jt * 64;
    float* O = out + (size_t)e * TPE * NH + (size_t)jt * 64;

    f32x4 acc[4];
    for (int nf = 0; nf < 4; ++nf) acc[nf] = f32x4{0.f, 0.f, 0.f, 0.f};

    for (int kt = 0; kt < NF / 64; ++kt) {   // 44 iters
        __syncthreads();
        #pragma unroll
        for (int r = 0; r < 2; ++r) {
            const int q   = tid + r * 256;
            const int row = q >> 3;
            const int k8  = (q & 7) * 8;
            *(bf16x8*)(&lA[row * PITCH + k8]) =
                *(const bf16x8*)(A + (size_t)row * NF + kt * 64 + k8);
        }
        {
            const int n  = tid & 63;
            const int kq = (tid >> 6) * 4;
            #pragma unroll
            for (int r = 0; r < 4; ++r) {
                const int ks = kq + r * 16;
                const size_t base = (size_t)(kt * 64 + ks) * NH + n;
                const float f0 = B[base];
                const float f1 = B[base + NH];
                const float f2 = B[base + 2 * (size_t)NH];
                const float f3 = B[base + 3 * (size_t)NH];
                ushort4 b;
                b.x = f2bf(f0); b.y = f2bf(f1); b.z = f2bf(f2); b.w = f2bf(f3);
                *(ushort4*)(&lB[n * PITCH + ks]) = b;
            }
        }
        __syncthreads();

        const int mrow = wid * 16 + (lane & 15);
        #pragma unroll
        for (int ks = 0; ks < 2; ++ks) {
            const int koff = ks * 32 + ((lane >> 4) * 8);
            const bf16x8 af = *(const bf16x8*)(&lA[mrow * PITCH + koff]);
            #pragma unroll
            for (int nf = 0; nf < 4; ++nf) {
                const bf16x8 bfr = *(const bf16x8*)(&lB[(nf * 16 + (lane & 15)) * PITCH + koff]);
                acc[nf] = __builtin_amdgcn_mfma_f32_16x16x32_bf16(af, bfr, acc[nf], 0, 0, 0);
            }
        }
    }

    #pragma unroll
    for (int nf = 0; nf < 4; ++nf) {
        #pragma unroll
        for (int i = 0; i < 4; ++i) {
            const int row = wid * 16 + ((lane >> 4) * 4) + i;
            const int col = nf * 16 + (lane & 15);
            O[(size_t)row * NH + col] = acc[nf][i];
        }
    }
}

extern "C" void kernel_launch(void* const* d_in, const int* in_sizes, int n_in,
                              void* d_out, int out_size, void* d_ws, size_t ws_size,
                              hipStream_t stream) {
    const float* x  = (const float*)d_in[0];
    const float* w1 = (const float*)d_in[2];
    const float* w3 = (const float*)d_in[3];
    const float* w2 = (const float*)d_in[4];
    float* out = (float*)d_out;
    ushort* gated = (ushort*)d_ws;                         // 23.1 MB
    ushort* xbf   = (ushort*)((char*)d_ws + (32u << 20));  // 8.4 MB @ +32MB
    ushort* h1    = (ushort*)((char*)d_ws + (48u << 20));  // 23.1 MB @ +48MB

    xcast<<<dim3((TPE * NE * NH) / (256 * 8)), dim3(256), 0, stream>>>(x, xbf);

    dim3 g1(NF / 64, NE);    // (44, 64)
    k1_mm<0><<<g1, dim3(256), 0, stream>>>(xbf, w1, nullptr, h1);   // h1 = x@w1^T
    k1_mm<1><<<g1, dim3(256), 0, stream>>>(xbf, w3, h1, gated);     // gated = silu(h1)*(x@w3^T)

    dim3 g2(NH / 64, NE);    // (16, 64)
    k2_down<<<g2, dim3(256), 0, stream>>>(gated, w2, out);
}